// Round 1
// baseline (376.654 us; speedup 1.0000x reference)
//
#include <hip/hip_runtime.h>

#define BT 4096      // B*T
#define Dd 1024
#define Tt 2048

typedef __attribute__((ext_vector_type(8))) short bf16x8;
typedef __attribute__((ext_vector_type(4))) float f32x4;

__device__ __forceinline__ short f2bf(float f) {
  unsigned u = __builtin_bit_cast(unsigned, f);
  u = (u + 0x7FFFu + ((u >> 16) & 1u)) >> 16;
  return (short)u;
}

__device__ __forceinline__ void load_lds16(const void* gsrc, void* ldst) {
  __builtin_amdgcn_global_load_lds(
      (const __attribute__((address_space(1))) void*)gsrc,
      (__attribute__((address_space(3))) void*)ldst, 16, 0, 0);
}

// ---------------- x fp32 -> bf16 ----------------
__global__ __launch_bounds__(256) void k_cvt(const float* __restrict__ src,
                                             short* __restrict__ dst, int n4) {
  int i = blockIdx.x * 256 + threadIdx.x;
  if (i >= n4) return;
  float4 v = ((const float4*)src)[i];
  short4 o;
  o.x = f2bf(v.x); o.y = f2bf(v.y); o.z = f2bf(v.z); o.w = f2bf(v.w);
  ((short4*)dst)[i] = o;
}

// ---------------- weight transpose: src [K][N] f32 -> dst [N][K] bf16 ----------------
__global__ __launch_bounds__(256) void k_wt(const float* __restrict__ src,
                                            short* __restrict__ dst, int K, int N) {
  int i = blockIdx.x * 256 + threadIdx.x;
  if (i >= K * N) return;
  int n = i % N, k = i / N;
  dst[(size_t)n * K + k] = f2bf(src[i]);
}

// ---------------- generic bf16 MFMA GEMM: C[M,N] = A[M,K] @ Bt[N,K]^T + bias ----------
// mode 0: fp32 C with ldc.  mode 1: qkv split -> oq/ok [b,h,t,dh] bf16, ov=vtmp [b,t,D] bf16.
__global__ __launch_bounds__(256) void k_gemm(
    const short* __restrict__ A, const short* __restrict__ Bt,
    const float* __restrict__ bias, float* __restrict__ C,
    short* __restrict__ oq, short* __restrict__ ok_, short* __restrict__ ov,
    int M, int N, int K, int ldc, int mode) {
  __shared__ short As[128 * 32];
  __shared__ short Bs[128 * 32];
  const int tid = threadIdx.x;
  const int wave = tid >> 6, lane = tid & 63;
  const int bm = blockIdx.y * 128, bn = blockIdx.x * 128;
  const int wr = (wave >> 1) * 64, wc = (wave & 1) * 64;
  const int row = lane & 15, g = lane >> 4;
  f32x4 acc[4][4] = {};
  const int kTiles = K >> 5;
  for (int kt = 0; kt < kTiles; ++kt) {
    const int k0 = kt << 5;
    __syncthreads();
#pragma unroll
    for (int j = 0; j < 2; ++j) {
      int slot = (wave * 2 + j) * 64 + lane;
      int r = slot >> 2, s = slot & 3;
      load_lds16(A + (size_t)(bm + r) * K + k0 + s * 8, &As[slot * 8]);
      load_lds16(Bt + (size_t)(bn + r) * K + k0 + s * 8, &Bs[slot * 8]);
    }
    __syncthreads();
    bf16x8 af[4], bfr[4];
#pragma unroll
    for (int mi = 0; mi < 4; ++mi)
      af[mi] = *(const bf16x8*)&As[(wr + mi * 16 + row) * 32 + g * 8];
#pragma unroll
    for (int ni = 0; ni < 4; ++ni)
      bfr[ni] = *(const bf16x8*)&Bs[(wc + ni * 16 + row) * 32 + g * 8];
#pragma unroll
    for (int mi = 0; mi < 4; ++mi)
#pragma unroll
      for (int ni = 0; ni < 4; ++ni)
        acc[mi][ni] = __builtin_amdgcn_mfma_f32_16x16x32_bf16(af[mi], bfr[ni],
                                                              acc[mi][ni], 0, 0, 0);
  }
  const int row4 = g * 4;
#pragma unroll
  for (int mi = 0; mi < 4; ++mi)
#pragma unroll
    for (int ni = 0; ni < 4; ++ni) {
      int c = bn + wc + ni * 16 + row;
      if (c >= N) continue;
      float badd = bias ? bias[c] : 0.f;
#pragma unroll
      for (int rg = 0; rg < 4; ++rg) {
        int r = bm + wr + mi * 16 + row4 + rg;
        float val = acc[mi][ni][rg] + badd;
        if (mode == 0) {
          C[(size_t)r * ldc + c] = val;
        } else {
          int b = r >> 11, t = r & 2047;
          int sel = c >> 10, rem = c & 1023;
          short bv = f2bf(val);
          if (sel == 0)
            oq[((size_t)(b * 16 + (rem >> 6)) * 2048 + t) * 64 + (rem & 63)] = bv;
          else if (sel == 1)
            ok_[((size_t)(b * 16 + (rem >> 6)) * 2048 + t) * 64 + (rem & 63)] = bv;
          else
            ov[(size_t)(b * 2048 + t) * 1024 + rem] = bv;
        }
      }
    }
}

// ---------------- V transpose: vtmp [b,t,(h,dh)] bf16 -> vb [b,h,dh,t] bf16 ----------
__global__ __launch_bounds__(256) void k_vtrans(const short* __restrict__ vtmp,
                                                short* __restrict__ vb) {
  __shared__ short tile[64][68];
  const int bh = blockIdx.x, b = bh >> 4, h = bh & 15;
  const int t0 = blockIdx.y * 64;
  const int tid = threadIdx.x;
#pragma unroll
  for (int pass = 0; pass < 16; ++pass) {
    int r = pass * 4 + (tid >> 6);
    int c = tid & 63;
    tile[r][c] = vtmp[((size_t)(b * 2048) + t0 + r) * 1024 + h * 64 + c];
  }
  __syncthreads();
#pragma unroll
  for (int pass = 0; pass < 16; ++pass) {
    int r = pass * 4 + (tid >> 6);  // dh
    int c = tid & 63;               // t offset
    vb[(((size_t)b * 16 + h) * 64 + r) * 2048 + t0 + c] = tile[c][r];
  }
}

// ---------------- causal flash attention ----------------
// Q,K: [b,h,t,dh] bf16 ; V: [b,h,dh,t] bf16 ; out: seqo [b,t,D] fp32
__global__ __launch_bounds__(256) void k_attn(const short* __restrict__ Q,
                                              const short* __restrict__ Kg,
                                              const short* __restrict__ Vg,
                                              float* __restrict__ seqo) {
  __shared__ short Kt[64 * 64];
  __shared__ short Vt[64 * 64];
  __shared__ short Pl[4][16 * 64];
  const int bh = blockIdx.x, qt = blockIdx.y;
  const int b = bh >> 4, h = bh & 15;
  const int tid = threadIdx.x, wave = tid >> 6, lane = tid & 63;
  const int row = lane & 15, g = lane >> 4;
  const short* qrowp = Q + ((size_t)bh * 2048 + qt * 64 + wave * 16 + row) * 64;
  bf16x8 qa[2];
  qa[0] = *(const bf16x8*)&qrowp[g * 8];
  qa[1] = *(const bf16x8*)&qrowp[32 + g * 8];
  f32x4 o[4] = {};
  float mrow[4] = {-1e30f, -1e30f, -1e30f, -1e30f};
  float lrow[4] = {0.f, 0.f, 0.f, 0.f};
  const short* kgb = Kg + (size_t)bh * 2048 * 64;
  const short* vgb = Vg + (size_t)bh * 64 * 2048;
  short* pw = &Pl[wave][0];
  const int nkv = qt + 1;
  for (int kt = 0; kt < nkv; ++kt) {
    const int kv0 = kt * 64;
    __syncthreads();
#pragma unroll
    for (int j = 0; j < 2; ++j) {
      int slot = (wave * 2 + j) * 64 + lane;
      int r = slot >> 3, s = slot & 7;
      int ss = s ^ (r & 7);  // both-sides XOR swizzle (linear LDS dest, swizzled source)
      load_lds16(kgb + (size_t)(kv0 + r) * 64 + ss * 8, &Kt[slot * 8]);
      load_lds16(vgb + (size_t)r * 2048 + kv0 + ss * 8, &Vt[slot * 8]);
    }
    __syncthreads();
    f32x4 s4[4];
#pragma unroll
    for (int nt = 0; nt < 4; ++nt) {
      int krow = nt * 16 + row;
      f32x4 s = {0.f, 0.f, 0.f, 0.f};
#pragma unroll
      for (int kc = 0; kc < 2; ++kc) {
        int sl = (kc * 4 + g) ^ (krow & 7);
        bf16x8 bb = *(const bf16x8*)&Kt[krow * 64 + sl * 8];
        s = __builtin_amdgcn_mfma_f32_16x16x32_bf16(qa[kc], bb, s, 0, 0, 0);
      }
      s4[nt] = s;
    }
    float mt[4];
#pragma unroll
    for (int rg = 0; rg < 4; ++rg) {
      int qr = qt * 64 + wave * 16 + g * 4 + rg;
      float mx = -1e30f;
#pragma unroll
      for (int nt = 0; nt < 4; ++nt) {
        int kcix = kv0 + nt * 16 + row;
        float v = s4[nt][rg] * 0.125f;
        v = (kcix <= qr) ? v : -1e30f;
        s4[nt][rg] = v;
        mx = fmaxf(mx, v);
      }
      mt[rg] = mx;
    }
#pragma unroll
    for (int off = 1; off < 16; off <<= 1)
#pragma unroll
      for (int rg = 0; rg < 4; ++rg)
        mt[rg] = fmaxf(mt[rg], __shfl_xor(mt[rg], off, 64));
    float sf[4], rs[4];
#pragma unroll
    for (int rg = 0; rg < 4; ++rg) {
      float mnew = fmaxf(mrow[rg], mt[rg]);
      sf[rg] = __expf(mrow[rg] - mnew);
      mrow[rg] = mnew;
      float a = 0.f;
#pragma unroll
      for (int nt = 0; nt < 4; ++nt) {
        float p = __expf(s4[nt][rg] - mnew);
        s4[nt][rg] = p;
        a += p;
      }
      rs[rg] = a;
    }
#pragma unroll
    for (int off = 1; off < 16; off <<= 1)
#pragma unroll
      for (int rg = 0; rg < 4; ++rg) rs[rg] += __shfl_xor(rs[rg], off, 64);
#pragma unroll
    for (int rg = 0; rg < 4; ++rg) lrow[rg] = lrow[rg] * sf[rg] + rs[rg];
#pragma unroll
    for (int nt = 0; nt < 4; ++nt)
#pragma unroll
      for (int rg = 0; rg < 4; ++rg) o[nt][rg] *= sf[rg];
    // write P (bf16, swizzled) to per-wave LDS
#pragma unroll
    for (int nt = 0; nt < 4; ++nt) {
      int col = nt * 16 + row;
#pragma unroll
      for (int rg = 0; rg < 4; ++rg) {
        int r = g * 4 + rg;
        pw[r * 64 + (((col >> 3) ^ (r & 7)) * 8) + (col & 7)] = f2bf(s4[nt][rg]);
      }
    }
    // P @ V
#pragma unroll
    for (int kc = 0; kc < 2; ++kc) {
      int sl = (kc * 4 + g) ^ (row & 7);
      bf16x8 pa = *(const bf16x8*)&pw[row * 64 + sl * 8];
#pragma unroll
      for (int nt = 0; nt < 4; ++nt) {
        int vr = nt * 16 + row;
        int slv = (kc * 4 + g) ^ (vr & 7);
        bf16x8 vbf = *(const bf16x8*)&Vt[vr * 64 + slv * 8];
        o[nt] = __builtin_amdgcn_mfma_f32_16x16x32_bf16(pa, vbf, o[nt], 0, 0, 0);
      }
    }
  }
#pragma unroll
  for (int nt = 0; nt < 4; ++nt)
#pragma unroll
    for (int rg = 0; rg < 4; ++rg) {
      int qr = qt * 64 + wave * 16 + g * 4 + rg;
      seqo[((size_t)b * 2048 + qr) * 1024 + h * 64 + nt * 16 + row] =
          o[nt][rg] / lrow[rg];
    }
}

// ---------------- Plücker lines: Csm [b,t,272] -> u=(wl@J)/|wl|, r=rl/|rl| [b,h,t,6] -
__global__ __launch_bounds__(256) void k_lines(const float* __restrict__ Cs,
                                               const float* __restrict__ Jm,
                                               float* __restrict__ u,
                                               float* __restrict__ rr) {
  int idx = blockIdx.x * 256 + threadIdx.x;
  if (idx >= 2 * 2048 * 16) return;
  int h = idx & 15, t = (idx >> 4) & 2047, b = idx >> 15;
  const float* rowx = Cs + (size_t)(b * 2048 + t) * 272;
  float w1[4], w2[4], r1[4], r2[4];
  if (t == 0) {
#pragma unroll
    for (int i = 0; i < 4; ++i) w1[i] = 0.f;
  } else {
    const float* prev = Cs + (size_t)(b * 2048 + t - 1) * 272;
#pragma unroll
    for (int i = 0; i < 4; ++i) w1[i] = prev[h * 4 + i];
  }
#pragma unroll
  for (int i = 0; i < 4; ++i) {
    w2[i] = rowx[64 + h * 4 + i];
    r1[i] = rowx[128 + h * 4 + i];
    r2[i] = rowx[192 + h * 4 + i];
  }
  const int pi[6] = {0, 0, 0, 1, 1, 2}, pj[6] = {1, 2, 3, 2, 3, 3};
  float wl[6], rl[6], nw = 0.f, nr = 0.f;
#pragma unroll
  for (int e = 0; e < 6; ++e) {
    wl[e] = w1[pi[e]] * w2[pj[e]] - w1[pj[e]] * w2[pi[e]];
    rl[e] = r1[pi[e]] * r2[pj[e]] - r1[pj[e]] * r2[pi[e]];
    nw += wl[e] * wl[e];
    nr += rl[e] * rl[e];
  }
  nw = 1.f / fmaxf(sqrtf(nw), 1e-12f);
  nr = 1.f / fmaxf(sqrtf(nr), 1e-12f);
  size_t base = (((size_t)b * 16 + h) * 2048 + t) * 6;
#pragma unroll
  for (int jc = 0; jc < 6; ++jc) {
    float s = 0.f;
#pragma unroll
    for (int i = 0; i < 6; ++i) s += wl[i] * Jm[i * 6 + jc];
    u[base + jc] = s * nw;
    rr[base + jc] = rl[jc] * nr;
  }
}

// ---------------- chunked decay scan: scores[b,h,t] = r_t^T S_t r_t ----------------
__global__ __launch_bounds__(1024) void k_scan(const float* __restrict__ u,
                                               const float* __restrict__ rr,
                                               float* __restrict__ scores,
                                               const float* __restrict__ decays) {
  __shared__ float Cst[16][36];
  const int bh = blockIdx.x;
  const float d = decays[bh & 15];
  const int tid = threadIdx.x, wave = tid >> 6, lane = tid & 63;
  const bool act = lane < 36;
  const int p = act ? lane / 6 : 0, q = act ? lane % 6 : 0;
  const float* ub = u + (size_t)bh * 2048 * 6;
  const float* rb = rr + (size_t)bh * 2048 * 6;
  const int t0 = wave * 128;
  // phase 1: per-chunk decayed outer-product sum
  float c = 0.f;
  for (int t = t0; t < t0 + 128; ++t) {
    float up = ub[t * 6 + p], uq = ub[t * 6 + q];
    c = d * (c + up * uq);
  }
  if (act) Cst[wave][lane] = c;
  __syncthreads();
  float dL = d;
#pragma unroll
  for (int i = 0; i < 7; ++i) dL *= dL;  // d^128
  // phase 2: prefix combine (each wave its own incoming state)
  float S = 0.f;
  for (int cc = 0; cc < wave; ++cc) S = S * dL + (act ? Cst[cc][lane] : 0.f);
  // phase 3: local scan with scores
  for (int t = t0; t < t0 + 128; ++t) {
    float rp = act ? rb[t * 6 + p] : 0.f;
    float rq = act ? rb[t * 6 + q] : 0.f;
    float contrib = rp * rq * S;
#pragma unroll
    for (int off = 1; off < 64; off <<= 1) contrib += __shfl_xor(contrib, off, 64);
    if (lane == 0) scores[(size_t)bh * 2048 + t] = contrib;
    float up = act ? ub[t * 6 + p] : 0.f;
    float uq = act ? ub[t * 6 + q] : 0.f;
    S = d * (S + up * uq);
  }
}

// ---------------- gate: gmean[b,t] = mean_h sig(score*scale_h)*sig(memg) -----------
__global__ __launch_bounds__(256) void k_gate(const float* __restrict__ scores,
                                              const float* __restrict__ Cs,
                                              const float* __restrict__ memg_b,
                                              const float* __restrict__ mem_scale,
                                              float* __restrict__ gmean) {
  int idx = blockIdx.x * 256 + threadIdx.x;
  if (idx >= BT) return;
  int b = idx >> 11, t = idx & 2047;
  float acc = 0.f;
#pragma unroll
  for (int h = 0; h < 16; ++h) {
    float s = scores[((size_t)(b * 16 + h) * 2048) + t];
    float gl = Cs[(size_t)idx * 272 + 256 + h] + memg_b[h];
    float a = 1.f / (1.f + __expf(-s * mem_scale[h]));
    float gg = 1.f / (1.f + __expf(-gl));
    acc += a * gg;
  }
  gmean[idx] = acc * (1.f / 16.f);
}

// ---------------- fuse: Fb = bf16(seq + gmean*memval) ----------------
__global__ __launch_bounds__(256) void k_fuse(const float* __restrict__ s,
                                              const float* __restrict__ mv,
                                              const float* __restrict__ gm,
                                              short* __restrict__ dst, int n4) {
  int i = blockIdx.x * 256 + threadIdx.x;
  if (i >= n4) return;
  float gg = gm[i >> 8];
  float4 a = ((const float4*)s)[i];
  float4 m = ((const float4*)mv)[i];
  short4 o;
  o.x = f2bf(a.x + gg * m.x);
  o.y = f2bf(a.y + gg * m.y);
  o.z = f2bf(a.z + gg * m.z);
  o.w = f2bf(a.w + gg * m.w);
  ((short4*)dst)[i] = o;
}

extern "C" void kernel_launch(void* const* d_in, const int* in_sizes, int n_in,
                              void* d_out, int out_size, void* d_ws, size_t ws_size,
                              hipStream_t stream) {
  const float* x = (const float*)d_in[0];
  const float* qkv_w = (const float*)d_in[1];
  const float* qkv_b = (const float*)d_in[2];
  const float* w1w = (const float*)d_in[3];
  const float* w2w = (const float*)d_in[4];
  const float* w1r = (const float*)d_in[5];
  const float* w2r = (const float*)d_in[6];
  const float* memv_w = (const float*)d_in[7];
  const float* memv_b = (const float*)d_in[8];
  const float* memg_w = (const float*)d_in[9];
  const float* memg_b = (const float*)d_in[10];
  const float* mem_scale = (const float*)d_in[11];
  const float* out_w = (const float*)d_in[12];
  const float* out_b = (const float*)d_in[13];
  const float* Jm = (const float*)d_in[14];
  const float* decays = (const float*)d_in[15];

  char* w = (char*)d_ws;
  size_t off = 0;
  auto alloc = [&](size_t bytes) -> void* {
    void* p = w + off;
    off += (bytes + 255) & ~(size_t)255;
    return p;
  };
  short* xb = (short*)alloc((size_t)BT * Dd * 2);
  short* WTqkv = (short*)alloc((size_t)3072 * 1024 * 2);
  short* WTsm = (short*)alloc((size_t)384 * 1024 * 2);
  short* WTmv = (short*)alloc((size_t)1024 * 1024 * 2);
  short* WTout = (short*)alloc((size_t)1024 * 1024 * 2);
  short* qb = (short*)alloc((size_t)32 * 2048 * 64 * 2);
  short* kb = (short*)alloc((size_t)32 * 2048 * 64 * 2);
  short* vtmp = (short*)alloc((size_t)BT * 1024 * 2);
  short* vb = (short*)alloc((size_t)32 * 64 * 2048 * 2);
  float* Csm = (float*)alloc((size_t)BT * 272 * 4);
  float* ua = (float*)alloc((size_t)32 * 2048 * 6 * 4);
  float* ra = (float*)alloc((size_t)32 * 2048 * 6 * 4);
  float* sc = (float*)alloc((size_t)32 * 2048 * 4);
  float* gm = (float*)alloc((size_t)BT * 4);
  float* mval = (float*)alloc((size_t)BT * 1024 * 4);
  float* seqo = (float*)alloc((size_t)BT * 1024 * 4);
  float* Fbuf = (float*)alloc(256);  // spacer (unused)
  short* Fb = (short*)alloc((size_t)BT * Dd * 2);
  (void)Fbuf; (void)ws_size; (void)in_sizes; (void)n_in; (void)out_size;

  // prep
  k_cvt<<<(BT * Dd / 4 + 255) / 256, 256, 0, stream>>>(x, xb, BT * Dd / 4);
  k_wt<<<(1024 * 3072 + 255) / 256, 256, 0, stream>>>(qkv_w, WTqkv, 1024, 3072);
  k_wt<<<(1024 * 64 + 255) / 256, 256, 0, stream>>>(w1w, WTsm + (size_t)0 * 1024, 1024, 64);
  k_wt<<<(1024 * 64 + 255) / 256, 256, 0, stream>>>(w2w, WTsm + (size_t)64 * 1024, 1024, 64);
  k_wt<<<(1024 * 64 + 255) / 256, 256, 0, stream>>>(w1r, WTsm + (size_t)128 * 1024, 1024, 64);
  k_wt<<<(1024 * 64 + 255) / 256, 256, 0, stream>>>(w2r, WTsm + (size_t)192 * 1024, 1024, 64);
  k_wt<<<(1024 * 16 + 255) / 256, 256, 0, stream>>>(memg_w, WTsm + (size_t)256 * 1024, 1024, 16);
  k_wt<<<(1024 * 1024 + 255) / 256, 256, 0, stream>>>(memv_w, WTmv, 1024, 1024);
  k_wt<<<(1024 * 1024 + 255) / 256, 256, 0, stream>>>(out_w, WTout, 1024, 1024);

  // GEMMs
  k_gemm<<<dim3(24, 32), 256, 0, stream>>>(xb, WTqkv, qkv_b, nullptr, qb, kb, vtmp,
                                           BT, 3072, 1024, 0, 1);
  k_vtrans<<<dim3(32, 32), 256, 0, stream>>>(vtmp, vb);
  k_gemm<<<dim3(3, 32), 256, 0, stream>>>(xb, WTsm, nullptr, Csm, nullptr, nullptr,
                                          nullptr, BT, 272, 1024, 272, 0);
  k_gemm<<<dim3(8, 32), 256, 0, stream>>>(xb, WTmv, memv_b, mval, nullptr, nullptr,
                                          nullptr, BT, 1024, 1024, 1024, 0);

  // attention
  k_attn<<<dim3(32, 32), 256, 0, stream>>>(qb, kb, vb, seqo);

  // memory path
  k_lines<<<(2 * 2048 * 16 + 255) / 256, 256, 0, stream>>>(Csm, Jm, ua, ra);
  k_scan<<<32, 1024, 0, stream>>>(ua, ra, sc, decays);
  k_gate<<<(BT + 255) / 256, 256, 0, stream>>>(sc, Csm, memg_b, mem_scale, gm);

  // fuse + final GEMM
  k_fuse<<<(BT * Dd / 4 + 255) / 256, 256, 0, stream>>>(seqo, mval, gm, Fb, BT * Dd / 4);
  k_gemm<<<dim3(8, 32), 256, 0, stream>>>(Fb, WTout, out_b, (float*)d_out, nullptr,
                                          nullptr, nullptr, BT, 1024, 1024, 1024, 0);
}

// Round 2
// 293.335 us; speedup vs baseline: 1.2840x; 1.2840x over previous
//
#include <hip/hip_runtime.h>

#define BT 4096      // B*T
#define Dd 1024
#define Tt 2048

typedef __attribute__((ext_vector_type(8))) short bf16x8;
typedef __attribute__((ext_vector_type(4))) float f32x4;

__device__ __forceinline__ short f2bf(float f) {
  unsigned u = __builtin_bit_cast(unsigned, f);
  u = (u + 0x7FFFu + ((u >> 16) & 1u)) >> 16;
  return (short)u;
}

__device__ __forceinline__ void load_lds16(const void* gsrc, void* ldst) {
  __builtin_amdgcn_global_load_lds(
      (const __attribute__((address_space(1))) void*)gsrc,
      (__attribute__((address_space(3))) void*)ldst, 16, 0, 0);
}

// ---------------- x fp32 -> bf16 ----------------
__global__ __launch_bounds__(256) void k_cvt(const float* __restrict__ src,
                                             short* __restrict__ dst, int n4) {
  int i = blockIdx.x * 256 + threadIdx.x;
  if (i >= n4) return;
  float4 v = ((const float4*)src)[i];
  short4 o;
  o.x = f2bf(v.x); o.y = f2bf(v.y); o.z = f2bf(v.z); o.w = f2bf(v.w);
  ((short4*)dst)[i] = o;
}

// ------------- tiled weight transpose: src [K][N] f32 -> dst [N][K] bf16 -------------
__global__ __launch_bounds__(256) void k_wt2(const float* __restrict__ src,
                                             short* __restrict__ dst, int K, int N) {
  __shared__ float tile[64][65];
  const int n0 = blockIdx.x * 64, k0 = blockIdx.y * 64;
  const int c = threadIdx.x & 63, r4 = threadIdx.x >> 6;
#pragma unroll
  for (int i = 0; i < 16; ++i) {
    int r = i * 4 + r4;
    float v = 0.f;
    if (k0 + r < K && n0 + c < N) v = src[(size_t)(k0 + r) * N + n0 + c];
    tile[r][c] = v;
  }
  __syncthreads();
#pragma unroll
  for (int i = 0; i < 16; ++i) {
    int n = i * 4 + r4;
    if (n0 + n < N && k0 + c < K)
      dst[(size_t)(n0 + n) * K + k0 + c] = f2bf(tile[c][n]);
  }
}

// ---------------- generic bf16 MFMA GEMM: C[M,N] = A[M,K] @ Bt[N,K]^T + bias ----------
__global__ __launch_bounds__(256) void k_gemm(
    const short* __restrict__ A, const short* __restrict__ Bt,
    const float* __restrict__ bias, float* __restrict__ C,
    short* __restrict__ oq, short* __restrict__ ok_, short* __restrict__ ov,
    int M, int N, int K, int ldc, int mode) {
  __shared__ short As[128 * 32];
  __shared__ short Bs[128 * 32];
  const int tid = threadIdx.x;
  const int wave = tid >> 6, lane = tid & 63;
  const int bm = blockIdx.y * 128, bn = blockIdx.x * 128;
  const int wr = (wave >> 1) * 64, wc = (wave & 1) * 64;
  const int row = lane & 15, g = lane >> 4;
  f32x4 acc[4][4] = {};
  const int kTiles = K >> 5;
  for (int kt = 0; kt < kTiles; ++kt) {
    const int k0 = kt << 5;
    __syncthreads();
#pragma unroll
    for (int j = 0; j < 2; ++j) {
      int slot = (wave * 2 + j) * 64 + lane;
      int r = slot >> 2, s = slot & 3;
      load_lds16(A + (size_t)(bm + r) * K + k0 + s * 8, &As[slot * 8]);
      load_lds16(Bt + (size_t)(bn + r) * K + k0 + s * 8, &Bs[slot * 8]);
    }
    __syncthreads();
    bf16x8 af[4], bfr[4];
#pragma unroll
    for (int mi = 0; mi < 4; ++mi)
      af[mi] = *(const bf16x8*)&As[(wr + mi * 16 + row) * 32 + g * 8];
#pragma unroll
    for (int ni = 0; ni < 4; ++ni)
      bfr[ni] = *(const bf16x8*)&Bs[(wc + ni * 16 + row) * 32 + g * 8];
#pragma unroll
    for (int mi = 0; mi < 4; ++mi)
#pragma unroll
      for (int ni = 0; ni < 4; ++ni)
        acc[mi][ni] = __builtin_amdgcn_mfma_f32_16x16x32_bf16(af[mi], bfr[ni],
                                                              acc[mi][ni], 0, 0, 0);
  }
  const int row4 = g * 4;
#pragma unroll
  for (int mi = 0; mi < 4; ++mi)
#pragma unroll
    for (int ni = 0; ni < 4; ++ni) {
      int c = bn + wc + ni * 16 + row;
      if (c >= N) continue;
      float badd = bias ? bias[c] : 0.f;
#pragma unroll
      for (int rg = 0; rg < 4; ++rg) {
        int r = bm + wr + mi * 16 + row4 + rg;
        float val = acc[mi][ni][rg] + badd;
        if (mode == 0) {
          C[(size_t)r * ldc + c] = val;
        } else {
          int b = r >> 11, t = r & 2047;
          int sel = c >> 10, rem = c & 1023;
          short bv = f2bf(val);
          if (sel == 0)
            oq[((size_t)(b * 16 + (rem >> 6)) * 2048 + t) * 64 + (rem & 63)] = bv;
          else if (sel == 1)
            ok_[((size_t)(b * 16 + (rem >> 6)) * 2048 + t) * 64 + (rem & 63)] = bv;
          else
            ov[(size_t)(b * 2048 + t) * 1024 + rem] = bv;
        }
      }
    }
}

// ---------------- V transpose: vtmp [b,t,(h,dh)] bf16 -> vb [b,h,dh,t] bf16 ----------
__global__ __launch_bounds__(256) void k_vtrans(const short* __restrict__ vtmp,
                                                short* __restrict__ vb) {
  __shared__ short tile[64][68];
  const int bh = blockIdx.x, b = bh >> 4, h = bh & 15;
  const int t0 = blockIdx.y * 64;
  const int tid = threadIdx.x;
#pragma unroll
  for (int pass = 0; pass < 16; ++pass) {
    int r = pass * 4 + (tid >> 6);
    int c = tid & 63;
    tile[r][c] = vtmp[((size_t)(b * 2048) + t0 + r) * 1024 + h * 64 + c];
  }
  __syncthreads();
#pragma unroll
  for (int pass = 0; pass < 16; ++pass) {
    int r = pass * 4 + (tid >> 6);  // dh
    int c = tid & 63;               // t offset
    vb[(((size_t)b * 16 + h) * 64 + r) * 2048 + t0 + c] = tile[c][r];
  }
}

// ---------------- causal flash attention (paired q-tiles, double-buffered KV) -------
#define ATT_SCALE 0.18033688f  // 0.125 * log2(e)

__device__ __forceinline__ void attn_step(const bf16x8 qa[2], f32x4 o[4],
                                          float m[4], float l[4],
                                          const short* __restrict__ Ktb,
                                          const short* __restrict__ Vtb,
                                          short* __restrict__ pw,
                                          int qt, int kt, int wave, int lane) {
  const int row = lane & 15, g = lane >> 4;
  const int kv0 = kt * 64;
  const bool masked = (kt == qt);
  f32x4 s4[4];
#pragma unroll
  for (int nt = 0; nt < 4; ++nt) {
    int krow = nt * 16 + row;
    f32x4 s = {0.f, 0.f, 0.f, 0.f};
#pragma unroll
    for (int kc = 0; kc < 2; ++kc) {
      int sl = (kc * 4 + g) ^ (krow & 7);
      bf16x8 bb = *(const bf16x8*)&Ktb[krow * 64 + sl * 8];
      s = __builtin_amdgcn_mfma_f32_16x16x32_bf16(qa[kc], bb, s, 0, 0, 0);
    }
    s4[nt] = s;
  }
  float mt[4];
#pragma unroll
  for (int rg = 0; rg < 4; ++rg) {
    float mx = -1e30f;
    int qr = qt * 64 + wave * 16 + g * 4 + rg;
#pragma unroll
    for (int nt = 0; nt < 4; ++nt) {
      float v = s4[nt][rg] * ATT_SCALE;
      if (masked) {
        int kcix = kv0 + nt * 16 + row;
        v = (kcix <= qr) ? v : -1e30f;
      }
      s4[nt][rg] = v;
      mx = fmaxf(mx, v);
    }
    mt[rg] = mx;
  }
#pragma unroll
  for (int off = 1; off < 16; off <<= 1)
#pragma unroll
    for (int rg = 0; rg < 4; ++rg)
      mt[rg] = fmaxf(mt[rg], __shfl_xor(mt[rg], off, 64));
  float sf[4], rs[4];
#pragma unroll
  for (int rg = 0; rg < 4; ++rg) {
    float mnew = fmaxf(m[rg], mt[rg]);
    sf[rg] = __builtin_amdgcn_exp2f(m[rg] - mnew);
    m[rg] = mnew;
    float a = 0.f;
#pragma unroll
    for (int nt = 0; nt < 4; ++nt) {
      float p = __builtin_amdgcn_exp2f(s4[nt][rg] - mnew);
      s4[nt][rg] = p;
      a += p;
    }
    rs[rg] = a;
  }
#pragma unroll
  for (int off = 1; off < 16; off <<= 1)
#pragma unroll
    for (int rg = 0; rg < 4; ++rg) rs[rg] += __shfl_xor(rs[rg], off, 64);
#pragma unroll
  for (int rg = 0; rg < 4; ++rg) l[rg] = l[rg] * sf[rg] + rs[rg];
#pragma unroll
  for (int nt = 0; nt < 4; ++nt)
#pragma unroll
    for (int rg = 0; rg < 4; ++rg) o[nt][rg] *= sf[rg];
#pragma unroll
  for (int nt = 0; nt < 4; ++nt) {
    int col = nt * 16 + row;
#pragma unroll
    for (int rg = 0; rg < 4; ++rg) {
      int r = g * 4 + rg;
      pw[r * 64 + (((col >> 3) ^ (r & 7)) * 8) + (col & 7)] = f2bf(s4[nt][rg]);
    }
  }
#pragma unroll
  for (int kc = 0; kc < 2; ++kc) {
    int sl = (kc * 4 + g) ^ (row & 7);
    bf16x8 pa = *(const bf16x8*)&pw[row * 64 + sl * 8];
#pragma unroll
    for (int nt = 0; nt < 4; ++nt) {
      int vr = nt * 16 + row;
      int slv = (kc * 4 + g) ^ (vr & 7);
      bf16x8 vbf = *(const bf16x8*)&Vtb[vr * 64 + slv * 8];
      o[nt] = __builtin_amdgcn_mfma_f32_16x16x32_bf16(pa, vbf, o[nt], 0, 0, 0);
    }
  }
}

__device__ __forceinline__ void attn_out(const f32x4 o[4], const float l[4],
                                         float* __restrict__ seqo, int b, int h,
                                         int qt, int wave, int lane) {
  const int row = lane & 15, g = lane >> 4;
#pragma unroll
  for (int rg = 0; rg < 4; ++rg) {
    float inv = 1.f / l[rg];
    int qr = qt * 64 + wave * 16 + g * 4 + rg;
#pragma unroll
    for (int nt = 0; nt < 4; ++nt)
      seqo[((size_t)b * 2048 + qr) * 1024 + h * 64 + nt * 16 + row] = o[nt][rg] * inv;
  }
}

__global__ __launch_bounds__(256) void k_attn(const short* __restrict__ Q,
                                              const short* __restrict__ Kg,
                                              const short* __restrict__ Vg,
                                              float* __restrict__ seqo) {
  __shared__ short Kt[2][64 * 64];
  __shared__ short Vt[2][64 * 64];
  __shared__ short Pl[4][16 * 64];
  const int bh = blockIdx.x;            // 0..31
  const int qtA = blockIdx.y;           // 0..15
  const int qtB = 31 - qtA;
  const int b = bh >> 4, h = bh & 15;
  const int tid = threadIdx.x, wave = tid >> 6, lane = tid & 63;
  const int row = lane & 15, g = lane >> 4;
  const short* qbase = Q + (size_t)bh * 2048 * 64;
  bf16x8 qaA[2], qaB[2];
  {
    const short* qr = qbase + (qtA * 64 + wave * 16 + row) * 64;
    qaA[0] = *(const bf16x8*)&qr[g * 8];
    qaA[1] = *(const bf16x8*)&qr[32 + g * 8];
    qr = qbase + (qtB * 64 + wave * 16 + row) * 64;
    qaB[0] = *(const bf16x8*)&qr[g * 8];
    qaB[1] = *(const bf16x8*)&qr[32 + g * 8];
  }
  f32x4 oA[4] = {}, oB[4] = {};
  float mA[4] = {-1e30f, -1e30f, -1e30f, -1e30f}, lA[4] = {0.f, 0.f, 0.f, 0.f};
  float mB[4] = {-1e30f, -1e30f, -1e30f, -1e30f}, lB[4] = {0.f, 0.f, 0.f, 0.f};
  const short* kgb = Kg + (size_t)bh * 2048 * 64;
  const short* vgb = Vg + (size_t)bh * 64 * 2048;
  short* pw = &Pl[wave][0];

  auto stage = [&](int bi, int kt) {
    int kv0 = kt * 64;
#pragma unroll
    for (int j = 0; j < 2; ++j) {
      int slot = (wave * 2 + j) * 64 + lane;
      int r = slot >> 3, s = slot & 7;
      int ss = s ^ (r & 7);
      load_lds16(kgb + (size_t)(kv0 + r) * 64 + ss * 8, &Kt[bi][slot * 8]);
      load_lds16(vgb + (size_t)r * 2048 + kv0 + ss * 8, &Vt[bi][slot * 8]);
    }
  };

  const int nkv = qtB + 1;
  stage(0, 0);
  int cur = 0;
  for (int kt = 0; kt < nkv; ++kt) {
    __syncthreads();  // drains vmcnt: buf[cur] staged; buf[cur^1] free
    if (kt + 1 < nkv) stage(cur ^ 1, kt + 1);
    attn_step(qaB, oB, mB, lB, Kt[cur], Vt[cur], pw, qtB, kt, wave, lane);
    if (kt <= qtA)
      attn_step(qaA, oA, mA, lA, Kt[cur], Vt[cur], pw, qtA, kt, wave, lane);
    cur ^= 1;
  }
  attn_out(oA, lA, seqo, b, h, qtA, wave, lane);
  attn_out(oB, lB, seqo, b, h, qtB, wave, lane);
}

// ---------------- Plücker lines: Csm [b,t,272] -> u=(wl@J)/|wl|, r=rl/|rl| ----------
__global__ __launch_bounds__(256) void k_lines(const float* __restrict__ Cs,
                                               const float* __restrict__ Jm,
                                               float* __restrict__ u,
                                               float* __restrict__ rr) {
  int idx = blockIdx.x * 256 + threadIdx.x;
  if (idx >= 2 * 2048 * 16) return;
  int h = idx & 15, t = (idx >> 4) & 2047, b = idx >> 15;
  const float* rowx = Cs + (size_t)(b * 2048 + t) * 272;
  float w1[4], w2[4], r1[4], r2[4];
  if (t == 0) {
#pragma unroll
    for (int i = 0; i < 4; ++i) w1[i] = 0.f;
  } else {
    const float* prev = Cs + (size_t)(b * 2048 + t - 1) * 272;
#pragma unroll
    for (int i = 0; i < 4; ++i) w1[i] = prev[h * 4 + i];
  }
#pragma unroll
  for (int i = 0; i < 4; ++i) {
    w2[i] = rowx[64 + h * 4 + i];
    r1[i] = rowx[128 + h * 4 + i];
    r2[i] = rowx[192 + h * 4 + i];
  }
  const int pi[6] = {0, 0, 0, 1, 1, 2}, pj[6] = {1, 2, 3, 2, 3, 3};
  float wl[6], rl[6], nw = 0.f, nr = 0.f;
#pragma unroll
  for (int e = 0; e < 6; ++e) {
    wl[e] = w1[pi[e]] * w2[pj[e]] - w1[pj[e]] * w2[pi[e]];
    rl[e] = r1[pi[e]] * r2[pj[e]] - r1[pj[e]] * r2[pi[e]];
    nw += wl[e] * wl[e];
    nr += rl[e] * rl[e];
  }
  nw = 1.f / fmaxf(sqrtf(nw), 1e-12f);
  nr = 1.f / fmaxf(sqrtf(nr), 1e-12f);
  size_t base = (((size_t)b * 16 + h) * 2048 + t) * 6;
#pragma unroll
  for (int jc = 0; jc < 6; ++jc) {
    float s = 0.f;
#pragma unroll
    for (int i = 0; i < 6; ++i) s += wl[i] * Jm[i * 6 + jc];
    u[base + jc] = s * nw;
    rr[base + jc] = rl[jc] * nr;
  }
}

// ------------- decayed prefix scan per channel: w[bh][ch][t] = S_t[p][q] -------------
// S_t = sum_{j<t} d^{t-j} z_j,  z = u_p*u_q.  One block per (ch, bh): chunk-8 +
// Hillis-Steele (with decay multipliers) over 256 threads.
__global__ __launch_bounds__(256) void k_scanw(const float* __restrict__ u,
                                               float* __restrict__ w,
                                               const float* __restrict__ decays) {
  __shared__ float wtot[4];
  const int ch = blockIdx.x;   // 0..35
  const int bh = blockIdx.y;   // 0..31
  const float d = decays[bh & 15];
  const int p = ch / 6, q = ch % 6;
  const int tid = threadIdx.x, lane = tid & 63, wv = tid >> 6;
  const float* ub = u + (size_t)bh * 2048 * 6;
  const int t0 = tid * 8;
  float z[8];
  float a = 0.f;
#pragma unroll
  for (int i = 0; i < 8; ++i) {
    float up = ub[(t0 + i) * 6 + p], uq = ub[(t0 + i) * 6 + q];
    z[i] = up * uq;
    a = d * (a + z[i]);
  }
  // a = A_j : S_{8(j+1)} = d^8 * S_{8j} + A_j
  float d8 = d * d; d8 *= d8; d8 *= d8;
  float I = a;   // within-wave inclusive scan with multiplier d8
  float ds = d8;
#pragma unroll
  for (int s = 1; s < 64; s <<= 1) {
    float v = __shfl_up(I, s, 64);
    if (lane >= s) I += ds * v;
    ds *= ds;
  }
  // ds == d8^64 == d^512
  if (lane == 63) wtot[wv] = I;
  __syncthreads();
  float carry = 0.f;  // global inclusive at end of previous wave
  for (int w2 = 0; w2 < wv; ++w2) carry = carry * ds + wtot[w2];
  float dlp1 = exp2f(log2f(d8) * (float)(lane + 1));  // d8^(lane+1)
  float Ig = I + dlp1 * carry;
  float E = __shfl_up(Ig, 1, 64);  // exclusive: S at chunk start
  if (lane == 0) E = carry;
  float S = E;
  float out[8];
#pragma unroll
  for (int i = 0; i < 8; ++i) {
    out[i] = S;
    S = d * (S + z[i]);
  }
  float4* wp = (float4*)(w + ((size_t)bh * 36 + ch) * 2048 + t0);
  wp[0] = make_float4(out[0], out[1], out[2], out[3]);
  wp[1] = make_float4(out[4], out[5], out[6], out[7]);
}

// ------------- scores[bh][t] = sum_ch r[p]*r[q] * w[bh][ch][t] ----------------------
__global__ __launch_bounds__(256) void k_scandot(const float* __restrict__ rr,
                                                 const float* __restrict__ w,
                                                 float* __restrict__ scores) {
  const int bh = blockIdx.y;
  const int t = blockIdx.x * 256 + threadIdx.x;
  const float* rb = rr + ((size_t)bh * 2048 + t) * 6;
  float r[6];
#pragma unroll
  for (int i = 0; i < 6; ++i) r[i] = rb[i];
  const float* wb = w + (size_t)bh * 36 * 2048 + t;
  float acc = 0.f;
#pragma unroll
  for (int ch = 0; ch < 36; ++ch)
    acc += r[ch / 6] * r[ch % 6] * wb[(size_t)ch * 2048];
  scores[(size_t)bh * 2048 + t] = acc;
}

// ---------------- gate: gmean[b,t] = mean_h sig(score*scale_h)*sig(memg) -----------
__global__ __launch_bounds__(256) void k_gate(const float* __restrict__ scores,
                                              const float* __restrict__ Cs,
                                              const float* __restrict__ memg_b,
                                              const float* __restrict__ mem_scale,
                                              float* __restrict__ gmean) {
  int idx = blockIdx.x * 256 + threadIdx.x;
  if (idx >= BT) return;
  int b = idx >> 11, t = idx & 2047;
  float acc = 0.f;
#pragma unroll
  for (int h = 0; h < 16; ++h) {
    float s = scores[((size_t)(b * 16 + h) * 2048) + t];
    float gl = Cs[(size_t)idx * 272 + 256 + h] + memg_b[h];
    float a = 1.f / (1.f + __expf(-s * mem_scale[h]));
    float gg = 1.f / (1.f + __expf(-gl));
    acc += a * gg;
  }
  gmean[idx] = acc * (1.f / 16.f);
}

// ---------------- fuse: Fb = bf16(seq + gmean*memval) ----------------
__global__ __launch_bounds__(256) void k_fuse(const float* __restrict__ s,
                                              const float* __restrict__ mv,
                                              const float* __restrict__ gm,
                                              short* __restrict__ dst, int n4) {
  int i = blockIdx.x * 256 + threadIdx.x;
  if (i >= n4) return;
  float gg = gm[i >> 8];
  float4 a = ((const float4*)s)[i];
  float4 m = ((const float4*)mv)[i];
  short4 o;
  o.x = f2bf(a.x + gg * m.x);
  o.y = f2bf(a.y + gg * m.y);
  o.z = f2bf(a.z + gg * m.z);
  o.w = f2bf(a.w + gg * m.w);
  ((short4*)dst)[i] = o;
}

extern "C" void kernel_launch(void* const* d_in, const int* in_sizes, int n_in,
                              void* d_out, int out_size, void* d_ws, size_t ws_size,
                              hipStream_t stream) {
  const float* x = (const float*)d_in[0];
  const float* qkv_w = (const float*)d_in[1];
  const float* qkv_b = (const float*)d_in[2];
  const float* w1w = (const float*)d_in[3];
  const float* w2w = (const float*)d_in[4];
  const float* w1r = (const float*)d_in[5];
  const float* w2r = (const float*)d_in[6];
  const float* memv_w = (const float*)d_in[7];
  const float* memv_b = (const float*)d_in[8];
  const float* memg_w = (const float*)d_in[9];
  const float* memg_b = (const float*)d_in[10];
  const float* mem_scale = (const float*)d_in[11];
  const float* out_w = (const float*)d_in[12];
  const float* out_b = (const float*)d_in[13];
  const float* Jm = (const float*)d_in[14];
  const float* decays = (const float*)d_in[15];

  char* w = (char*)d_ws;
  size_t off = 0;
  auto alloc = [&](size_t bytes) -> void* {
    void* p = w + off;
    off += (bytes + 255) & ~(size_t)255;
    return p;
  };
  short* xb = (short*)alloc((size_t)BT * Dd * 2);
  short* WTqkv = (short*)alloc((size_t)3072 * 1024 * 2);
  short* WTsm = (short*)alloc((size_t)384 * 1024 * 2);
  short* WTmv = (short*)alloc((size_t)1024 * 1024 * 2);
  short* WTout = (short*)alloc((size_t)1024 * 1024 * 2);
  short* qb = (short*)alloc((size_t)32 * 2048 * 64 * 2);
  short* kb = (short*)alloc((size_t)32 * 2048 * 64 * 2);
  short* vtmp = (short*)alloc((size_t)BT * 1024 * 2);
  short* vb = (short*)alloc((size_t)32 * 64 * 2048 * 2);
  float* Csm = (float*)alloc((size_t)BT * 272 * 4);
  float* ua = (float*)alloc((size_t)32 * 2048 * 6 * 4);
  float* ra = (float*)alloc((size_t)32 * 2048 * 6 * 4);
  float* sc = (float*)alloc((size_t)32 * 2048 * 4);
  float* gm = (float*)alloc((size_t)BT * 4);
  float* mval = (float*)alloc((size_t)BT * 1024 * 4);
  float* seqo = (float*)alloc((size_t)BT * 1024 * 4);
  short* Fb = (short*)alloc((size_t)BT * Dd * 2);
  // scan state buffer (32*36*2048 fp32 = 9.4 MB) aliases qb+kb (16.8 MB),
  // which are dead after k_attn (stream-ordered before k_scanw).
  float* wscan = (float*)qb;
  (void)ws_size; (void)in_sizes; (void)n_in; (void)out_size;

  // prep
  k_cvt<<<(BT * Dd / 4 + 255) / 256, 256, 0, stream>>>(x, xb, BT * Dd / 4);
  k_wt2<<<dim3(48, 16), 256, 0, stream>>>(qkv_w, WTqkv, 1024, 3072);
  k_wt2<<<dim3(1, 16), 256, 0, stream>>>(w1w, WTsm + (size_t)0 * 1024, 1024, 64);
  k_wt2<<<dim3(1, 16), 256, 0, stream>>>(w2w, WTsm + (size_t)64 * 1024, 1024, 64);
  k_wt2<<<dim3(1, 16), 256, 0, stream>>>(w1r, WTsm + (size_t)128 * 1024, 1024, 64);
  k_wt2<<<dim3(1, 16), 256, 0, stream>>>(w2r, WTsm + (size_t)192 * 1024, 1024, 64);
  k_wt2<<<dim3(1, 16), 256, 0, stream>>>(memg_w, WTsm + (size_t)256 * 1024, 1024, 16);
  k_wt2<<<dim3(16, 16), 256, 0, stream>>>(memv_w, WTmv, 1024, 1024);
  k_wt2<<<dim3(16, 16), 256, 0, stream>>>(out_w, WTout, 1024, 1024);

  // GEMMs
  k_gemm<<<dim3(24, 32), 256, 0, stream>>>(xb, WTqkv, qkv_b, nullptr, qb, kb, vtmp,
                                           BT, 3072, 1024, 0, 1);
  k_vtrans<<<dim3(32, 32), 256, 0, stream>>>(vtmp, vb);
  k_gemm<<<dim3(3, 32), 256, 0, stream>>>(xb, WTsm, nullptr, Csm, nullptr, nullptr,
                                          nullptr, BT, 272, 1024, 272, 0);
  k_gemm<<<dim3(8, 32), 256, 0, stream>>>(xb, WTmv, memv_b, mval, nullptr, nullptr,
                                          nullptr, BT, 1024, 1024, 1024, 0);

  // attention (paired q-tiles: grid.y = 16)
  k_attn<<<dim3(32, 16), 256, 0, stream>>>(qb, kb, vb, seqo);

  // memory path
  k_lines<<<(2 * 2048 * 16 + 255) / 256, 256, 0, stream>>>(Csm, Jm, ua, ra);
  k_scanw<<<dim3(36, 32), 256, 0, stream>>>(ua, wscan, decays);
  k_scandot<<<dim3(8, 32), 256, 0, stream>>>(ra, wscan, sc);
  k_gate<<<(BT + 255) / 256, 256, 0, stream>>>(sc, Csm, memg_b, mem_scale, gm);

  // fuse + final GEMM
  k_fuse<<<(BT * Dd / 4 + 255) / 256, 256, 0, stream>>>(seqo, mval, gm, Fb, BT * Dd / 4);
  k_gemm<<<dim3(8, 32), 256, 0, stream>>>(Fb, WTout, out_b, (float*)d_out, nullptr,
                                          nullptr, nullptr, BT, 1024, 1024, 1024, 0);
}